// Round 9
// baseline (2077.839 us; speedup 1.0000x reference)
//
#include <hip/hip_runtime.h>

typedef _Float16 half8 __attribute__((ext_vector_type(8)));
typedef float f32x4 __attribute__((ext_vector_type(4)));

#define TT 48
#define BT 16
#define NSEQ 16384
#define NGRP (NSEQ / BT)
#define NTHR 512
#define WT 4
#define NWIN (TT / WT)
#define MAXGRID 512
#define H0_SLICE (TT * BT * 136)   // f16 elems per block ws slice (208896 B)

struct __align__(16) Smem {
  float gates[2 * 272 * 17];        // 36992 B  gate pre-activations [dir][gate][b(+pad)]
  _Float16 A[2 * 16 * 136];         //  8704 B  A panels (L0: x|h|bias; L1: h1|bias)
  _Float16 gxh[WT * 2 * 272 * 17];  // 73984 B  window gx, SAME layout as gates (f16)
  _Float16 h1w[WT * 16 * 136];      // 17408 B  parked h1 per window step (for FC)
  float ypart[320];                 //  1280 B
};                                  // 138368 B dynamic LDS

__device__ __forceinline__ float fast_rcp(float v) { return __builtin_amdgcn_rcpf(v); }
__device__ __forceinline__ float sigm(float v)  { return fast_rcp(1.f + __expf(-v)); }
__device__ __forceinline__ float tanh_s(float v){ return 1.f - 2.f * fast_rcp(1.f + __expf(2.f * v)); }

__global__ __attribute__((amdgpu_flat_work_group_size(NTHR, NTHR), amdgpu_waves_per_eu(2)))
void lstm_fc_kernel(
    const float* __restrict__ x,
    const float* __restrict__ Wih0f, const float* __restrict__ Whh0f,
    const float* __restrict__ bih0f, const float* __restrict__ bhh0f,
    const float* __restrict__ Wih0b, const float* __restrict__ Whh0b,
    const float* __restrict__ bih0b, const float* __restrict__ bhh0b,
    const float* __restrict__ Wih1f, const float* __restrict__ Whh1f,
    const float* __restrict__ bih1f, const float* __restrict__ bhh1f,
    const float* __restrict__ Wih1b, const float* __restrict__ Whh1b,
    const float* __restrict__ bih1b, const float* __restrict__ bhh1b,
    const float* __restrict__ fcw, const float* __restrict__ fcb,
    float* __restrict__ out, _Float16* __restrict__ ws)
{
  static_assert(sizeof(((Smem*)0)->A) == 544 * 16, "A zero covers 544 uint4");
  extern __shared__ char smem_raw[];
  Smem& s = *reinterpret_cast<Smem*>(smem_raw);
  const int tid = threadIdx.x;
  const int ln  = tid & 63;
  const int wid = tid >> 6;
  const int dw  = wid >> 2;               // wave direction: 0 fwd, 1 bwd
  const int wq  = wid & 3;
  const int NT    = (wq == 0) ? 5 : 4;    // recurrent N-tiles per wave (17/dir)
  const int tbase = (wq == 0) ? 0 : (1 + 4 * wq);
  const int lr = ln & 15;                 // tile row/col index
  const int lq = (ln >> 4) & 3;           // k-quad / batch-quad index

  const float* Wih0 = dw ? Wih0b : Wih0f;
  const float* Whh0 = dw ? Whh0b : Whh0f;
  const float* bih0 = dw ? bih0b : bih0f;
  const float* bhh0 = dw ? bhh0b : bhh0f;
  const float* Wih1 = dw ? Wih1b : Wih1f;
  const float* Whh1 = dw ? Whh1b : Whh1f;
  const float* bih1 = dw ? bih1b : bih1f;
  const float* bhh1 = dw ? bhh1b : bhh1f;

  // elementwise (d,b,j) pair ownership: 2176 pairs, 4 per thread + 128 extras
  int pd_[5], pb_[5], pj_[5];
  float cst[5];
  #pragma unroll
  for (int q = 0; q < 5; ++q) {
    const int p = (q < 4) ? (tid + 512 * q) : (2048 + (tid & 127));
    const int d = p / 1088;
    const int r = p - d * 1088;
    pd_[q] = d; pb_[q] = r / 68; pj_[q] = r - (r / 68) * 68;
  }

  // x staging tasks (1088 = 2 dirs x 16 b x 34 i)
  int sd0[3], sao0[3], sxo[3];
  #pragma unroll
  for (int u = 0; u < 3; ++u) {
    const int task = tid + 512 * u;
    const int tk = (task < 1088) ? task : 0;
    const int d = tk / 544;
    const int r = tk - d * 544;
    const int b = r / 34;
    const int i = r - b * 34;
    sd0[u]  = d;
    sao0[u] = d * 2176 + b * 136 + i;
    sxo[u]  = b * (TT * 34) + i;
  }

  // FC ownership: 320 threads = 16 b x 5 k x 4 slices
  int fb = 0, fk = 0, fs = 0;
  if (tid < 320) { fb = tid / 20; const int r = tid - fb * 20; fk = r >> 2; fs = r & 3; }
  float yp = 0.f;

  _Float16* h0w = ws + (size_t)blockIdx.x * H0_SLICE;

  for (int grp = blockIdx.x; grp < NGRP; grp += gridDim.x) {
    const float* xg = x + (size_t)grp * (BT * TT * 34);

    //================ PHASE A: layer-0 recurrence (K=128: x|h|bias) ================
    half8 Bf0[5][4];
    #pragma unroll
    for (int i = 0; i < 5; ++i) if (i < NT) {
      const int g = (tbase + i) * 16 + lr;
      #pragma unroll
      for (int kk = 0; kk < 4; ++kk) {
        half8 v;
        #pragma unroll
        for (int j = 0; j < 8; ++j) {
          const int k = kk * 32 + lq * 8 + j;
          float wv = 0.f;
          if (k < 34) wv = Wih0[g * 34 + k];
          else if (k < 102) wv = Whh0[g * 68 + (k - 34)];
          else if (k == 102) wv = bih0[g] + bhh0[g];
          v[j] = (_Float16)wv;
        }
        Bf0[i][kk] = v;
      }
    }
    #pragma unroll
    for (int q = 0; q < 5; ++q) cst[q] = 0.f;

    // zero FULL A panel: 544 uint4 with 512 threads -> two writes
    {
      const uint4 zz = {0, 0, 0, 0};
      ((uint4*)s.A)[tid] = zz;
      if (tid < 32) ((uint4*)s.A)[512 + tid] = zz;
    }
    __syncthreads();
    if (tid < 32) s.A[(tid >> 4) * 2176 + (tid & 15) * 136 + 102] = (_Float16)1.f;
    #pragma unroll
    for (int u = 0; u < 3; ++u)
      if (tid + 512 * u < 1088)
        s.A[sao0[u]] = (_Float16)xg[sxo[u] + (sd0[u] ? (TT - 1) * 34 : 0)];
    __syncthreads();

    #pragma unroll 1
    for (int st = 0; st < TT; ++st) {
      float xpf[3];
      if (st < TT - 1) {
        #pragma unroll
        for (int u = 0; u < 3; ++u)
          if (tid + 512 * u < 1088)
            xpf[u] = xg[sxo[u] + (sd0[u] ? (TT - 2 - st) : (st + 1)) * 34];
      }
      f32x4 acc[5];
      #pragma unroll
      for (int i = 0; i < 5; ++i) acc[i] = (f32x4){0.f, 0.f, 0.f, 0.f};
      #pragma unroll
      for (int kk = 0; kk < 4; ++kk) {
        const half8 a = *(const half8*)&s.A[dw * 2176 + lr * 136 + kk * 32 + lq * 8];
        #pragma unroll
        for (int i = 0; i < 5; ++i) if (i < NT)
          acc[i] = __builtin_amdgcn_mfma_f32_16x16x32_f16(a, Bf0[i][kk], acc[i], 0, 0, 0);
      }
      #pragma unroll
      for (int i = 0; i < 5; ++i) if (i < NT) {
        const int g = (tbase + i) * 16 + lr;
        #pragma unroll
        for (int r = 0; r < 4; ++r)
          s.gates[(dw * 272 + g) * 17 + lq * 4 + r] = acc[i][r];
      }
      __syncthreads();
      #pragma unroll
      for (int q = 0; q < 5; ++q) if (q < 4 || tid < 128) {
        const int gq = (pd_[q] * 272 + pj_[q]) * 17 + pb_[q];
        const float ii = sigm(s.gates[gq]);
        const float ff = sigm(s.gates[gq + 1156]);
        const float g2 = tanh_s(s.gates[gq + 2312]);
        const float oo = sigm(s.gates[gq + 3468]);
        const float cc = ff * cst[q] + ii * g2;
        cst[q] = cc;
        const float h = oo * tanh_s(cc);
        const _Float16 h16 = (_Float16)h;
        s.A[pd_[q] * 2176 + pb_[q] * 136 + 34 + pj_[q]] = h16;
        const int tq = pd_[q] ? (TT - 1 - st) : st;
        h0w[tq * 2176 + pb_[q] * 136 + pd_[q] * 68 + pj_[q]] = h16;
      }
      if (st < TT - 1) {
        #pragma unroll
        for (int u = 0; u < 3; ++u)
          if (tid + 512 * u < 1088) s.A[sao0[u]] = (_Float16)xpf[u];
      }
      __syncthreads();
    }

    //================ PHASE B: layer-1, windowed gx GEMM + K=96 recurrence ================
    {
      const uint4 zz = {0, 0, 0, 0};
      ((uint4*)s.A)[tid] = zz;
      if (tid < 32) ((uint4*)s.A)[512 + tid] = zz;
    }
    #pragma unroll
    for (int q = 0; q < 5; ++q) cst[q] = 0.f;
    __syncthreads();
    if (tid < 32) s.A[(tid >> 4) * 2176 + (tid & 15) * 136 + 68] = (_Float16)1.f;

    #pragma unroll 1
    for (int w = 0; w < NWIN; ++w) {
      // ---- gx GEMM: gx[b][g] = h0[t] . Wih1^T, written in gates-layout (f16) ----
      #pragma unroll 1
      for (int p = 0; p < 2; ++p) {
        const int slot = wq * 2 + p;
        const int nts = (slot == 0) ? 3 : 2;
        const int tbs = (slot == 0) ? 0 : (3 + 2 * (slot - 1));
        half8 Wf[3][5];
        #pragma unroll
        for (int i = 0; i < 3; ++i) if (i < nts) {
          const int g = (tbs + i) * 16 + lr;
          #pragma unroll
          for (int c = 0; c < 5; ++c) {
            const int k0 = c * 32 + lq * 8;
            half8 v = (half8){0, 0, 0, 0, 0, 0, 0, 0};
            if (k0 < 136) {
              const float4 w0 = *(const float4*)&Wih1[g * 136 + k0];
              const float4 w1 = *(const float4*)&Wih1[g * 136 + k0 + 4];
              v = (half8){(_Float16)w0.x, (_Float16)w0.y, (_Float16)w0.z, (_Float16)w0.w,
                          (_Float16)w1.x, (_Float16)w1.y, (_Float16)w1.z, (_Float16)w1.w};
            }
            Wf[i][c] = v;
          }
        }
        #pragma unroll 1
        for (int tp = 0; tp < WT; ++tp) {
          const int tw = w * WT + tp;
          const int tabs = dw ? (TT - 1 - tw) : tw;
          const _Float16* hrow = h0w + tabs * 2176 + lr * 136 + lq * 8;
          half8 af[5];
          #pragma unroll
          for (int c = 0; c < 4; ++c) af[c] = *(const half8*)(hrow + c * 32);
          af[4] = (lq == 0) ? *(const half8*)(hrow + 128) : (half8){0, 0, 0, 0, 0, 0, 0, 0};
          f32x4 acg[3];
          #pragma unroll
          for (int i = 0; i < 3; ++i) acg[i] = (f32x4){0.f, 0.f, 0.f, 0.f};
          #pragma unroll
          for (int c = 0; c < 5; ++c) {
            #pragma unroll
            for (int i = 0; i < 3; ++i) if (i < nts)
              acg[i] = __builtin_amdgcn_mfma_f32_16x16x32_f16(af[c], Wf[i][c], acg[i], 0, 0, 0);
          }
          // store C in gates-layout: row = batch = lq*4+r, col = gate = tile*16+lr
          #pragma unroll
          for (int i = 0; i < 3; ++i) if (i < nts) {
            const int g = (tbs + i) * 16 + lr;
            #pragma unroll
            for (int r = 0; r < 4; ++r)
              s.gxh[tp * 9248 + (dw * 272 + g) * 17 + lq * 4 + r] = (_Float16)acg[i][r];
          }
        }
      }
      // ---- recurrent B fragments (Whh1 + bias), K=96, reloaded per window ----
      half8 Bf1[5][3];
      #pragma unroll
      for (int i = 0; i < 5; ++i) if (i < NT) {
        const int g = (tbase + i) * 16 + lr;
        #pragma unroll
        for (int c = 0; c < 3; ++c) {
          half8 v = (half8){0, 0, 0, 0, 0, 0, 0, 0};
          if (c < 2) {
            const int k0 = c * 32 + lq * 8;
            const float4 w0 = *(const float4*)&Whh1[g * 68 + k0];
            const float4 w1 = *(const float4*)&Whh1[g * 68 + k0 + 4];
            v = (half8){(_Float16)w0.x, (_Float16)w0.y, (_Float16)w0.z, (_Float16)w0.w,
                        (_Float16)w1.x, (_Float16)w1.y, (_Float16)w1.z, (_Float16)w1.w};
          } else if (lq == 0) {
            const float4 w0 = *(const float4*)&Whh1[g * 68 + 64];
            v = (half8){(_Float16)w0.x, (_Float16)w0.y, (_Float16)w0.z, (_Float16)w0.w,
                        (_Float16)(bih1[g] + bhh1[g]), 0, 0, 0};
          }
          Bf1[i][c] = v;
        }
      }
      __syncthreads();   // gxh (and A-init on w==0) visible

      // ---- WT recurrent steps ----
      #pragma unroll 1
      for (int tp = 0; tp < WT; ++tp) {
        f32x4 acc[5];
        #pragma unroll
        for (int i = 0; i < 5; ++i) if (i < NT) {
          const int g = (tbase + i) * 16 + lr;
          #pragma unroll
          for (int r = 0; r < 4; ++r)
            acc[i][r] = (float)s.gxh[tp * 9248 + (dw * 272 + g) * 17 + lq * 4 + r];
        }
        #pragma unroll
        for (int kk = 0; kk < 3; ++kk) {
          const half8 a = *(const half8*)&s.A[dw * 2176 + lr * 136 + kk * 32 + lq * 8];
          #pragma unroll
          for (int i = 0; i < 5; ++i) if (i < NT)
            acc[i] = __builtin_amdgcn_mfma_f32_16x16x32_f16(a, Bf1[i][kk], acc[i], 0, 0, 0);
        }
        #pragma unroll
        for (int i = 0; i < 5; ++i) if (i < NT) {
          const int g = (tbase + i) * 16 + lr;
          #pragma unroll
          for (int r = 0; r < 4; ++r)
            s.gates[(dw * 272 + g) * 17 + lq * 4 + r] = acc[i][r];
        }
        __syncthreads();
        #pragma unroll
        for (int q = 0; q < 5; ++q) if (q < 4 || tid < 128) {
          const int gq = (pd_[q] * 272 + pj_[q]) * 17 + pb_[q];
          const float ii = sigm(s.gates[gq]);
          const float ff = sigm(s.gates[gq + 1156]);
          const float g2 = tanh_s(s.gates[gq + 2312]);
          const float oo = sigm(s.gates[gq + 3468]);
          const float cc = ff * cst[q] + ii * g2;
          cst[q] = cc;
          const float h = oo * tanh_s(cc);
          const _Float16 h16 = (_Float16)h;
          s.A[pd_[q] * 2176 + pb_[q] * 136 + pj_[q]] = h16;
          s.h1w[tp * 2176 + pb_[q] * 136 + pd_[q] * 68 + pj_[q]] = h16;
        }
        __syncthreads();
      }
      // ---- FC partials for this window (reads parked h1) ----
      if (tid < 320) {
        #pragma unroll
        for (int tp = 0; tp < WT; ++tp) {
          const int tw = w * WT + tp;
          const int tabs = (fs >= 2) ? (TT - 1 - tw) : tw;
          const int hb = tp * 2176 + fb * 136 + fs * 34;
          const int fo = fk * 6528 + tabs * 136 + fs * 34;
          float sa = 0.f;
          #pragma unroll
          for (int m = 0; m < 34; ++m)
            sa += (float)s.h1w[hb + m] * fcw[fo + m];
          yp += sa;
        }
      }
      __syncthreads();   // before next window's GEMM/park overwrite gxh/h1w
    }

    // ---- group epilogue ----
    if (tid < 320) s.ypart[tid] = yp;
    yp = 0.f;
    __syncthreads();
    if (tid < 80) {
      const int b = tid / 5, k = tid - (tid / 5) * 5;
      const float v = fcb[k]
        + s.ypart[b * 20 + k * 4 + 0] + s.ypart[b * 20 + k * 4 + 1]
        + s.ypart[b * 20 + k * 4 + 2] + s.ypart[b * 20 + k * 4 + 3];
      out[(size_t)(grp * BT + b) * 5 + k] = v;
    }
    __syncthreads();
  }
}

extern "C" void kernel_launch(void* const* d_in, const int* in_sizes, int n_in,
                              void* d_out, int out_size, void* d_ws, size_t ws_size,
                              hipStream_t stream) {
  (void)in_sizes; (void)n_in; (void)out_size;
  static_assert(sizeof(Smem) <= 160 * 1024, "LDS overflow");
  hipFuncSetAttribute((const void*)lstm_fc_kernel,
                      hipFuncAttributeMaxDynamicSharedMemorySize, (int)sizeof(Smem));

  const float* x     = (const float*)d_in[0];
  const float* Wih0f = (const float*)d_in[1];
  const float* Whh0f = (const float*)d_in[2];
  const float* bih0f = (const float*)d_in[3];
  const float* bhh0f = (const float*)d_in[4];
  const float* Wih0b = (const float*)d_in[5];
  const float* Whh0b = (const float*)d_in[6];
  const float* bih0b = (const float*)d_in[7];
  const float* bhh0b = (const float*)d_in[8];
  const float* Wih1f = (const float*)d_in[9];
  const float* Whh1f = (const float*)d_in[10];
  const float* bih1f = (const float*)d_in[11];
  const float* bhh1f = (const float*)d_in[12];
  const float* Wih1b = (const float*)d_in[13];
  const float* Whh1b = (const float*)d_in[14];
  const float* bih1b = (const float*)d_in[15];
  const float* bhh1b = (const float*)d_in[16];
  const float* fcw   = (const float*)d_in[17];
  const float* fcb   = (const float*)d_in[18];
  float* out = (float*)d_out;

  int slices = (int)(ws_size / (size_t)(H0_SLICE * 2));
  int grid = slices < 1 ? 1 : (slices > MAXGRID ? MAXGRID : slices);

  lstm_fc_kernel<<<dim3(grid), dim3(NTHR), sizeof(Smem), stream>>>(x,
      Wih0f, Whh0f, bih0f, bhh0f, Wih0b, Whh0b, bih0b, bhh0b,
      Wih1f, Whh1f, bih1f, bhh1f, Wih1b, Whh1b, bih1b, bhh1b,
      fcw, fcb, out, (_Float16*)d_ws);
}

// Round 10
// 1256.570 us; speedup vs baseline: 1.6536x; 1.6536x over previous
//
#include <hip/hip_runtime.h>

typedef _Float16 half8 __attribute__((ext_vector_type(8)));
typedef float f32x4 __attribute__((ext_vector_type(4)));

#define TT 48
#define BT 16
#define NSEQ 16384
#define NGRP (NSEQ / BT)
#define NTHR 512
#define MAXGRID 512
#define H0_SLICE (TT * BT * 136)   // f16 elems per block ws slice (208896 B)

// h0w layout: [t][d][b][j]  (stride per t = 2176 f16; full-line contiguous writes)
struct __align__(16) Smem {
  float gates[272 * 17];      // 18496 B  one-direction gate pre-activations [gate][b(+pad)]
  _Float16 A[16 * 232];       //  7424 B  A panel (L0 view: [16][136])
  float yscr[16 * 5 * 32];    // 10240 B  FC partial scratch
};                            // 36160 B static LDS -> 2 blocks/CU (VGPR <=128)

__device__ __forceinline__ float fast_rcp(float v) { return __builtin_amdgcn_rcpf(v); }
__device__ __forceinline__ float sigm(float v)  { return fast_rcp(1.f + __expf(-v)); }
__device__ __forceinline__ float tanh_s(float v){ return 1.f - 2.f * fast_rcp(1.f + __expf(2.f * v)); }

// One (layer, dir) recurrence, all 8 waves cooperating. 17 N-tiles: wave0 3, waves1-7 2.
template <int LAYER>
__device__ __forceinline__ void pass_lstm(Smem& s, const int d,
    const float* __restrict__ Wih, const float* __restrict__ Whh,
    const float* __restrict__ bih, const float* __restrict__ bhh,
    const float* __restrict__ xg,  const float* __restrict__ fcw,
    _Float16* __restrict__ h0w, float (&yk)[5])
{
  constexpr int AW   = LAYER ? 232 : 136;  // A row stride (f16)
  constexpr int KS   = LAYER ? 7 : 4;      // K chunks of 32 (224 / 128)
  constexpr int INW  = LAYER ? 136 : 34;   // non-recurrent width
  constexpr int BIASC = INW + 68;          // bias-one column (204 / 102)
  constexpr int HOFF = LAYER ? 136 : 34;   // h slot base in A row

  const int tid = threadIdx.x;
  const int ln = tid & 63, wid = tid >> 6;
  const int lr = ln & 15, lq = ln >> 4;
  const int NT = (wid == 0) ? 3 : 2;
  const int tbase = (wid == 0) ? 0 : (1 + 2 * wid);   // w0:0-2, w1:3-4, ..., w7:15-16
  const int b_ = tid >> 5, m_ = tid & 31;             // elementwise: b-uniform mapping

  // ---- B fragments in registers for all 48 steps (max 3*7*4 = 84 VGPR) ----
  half8 Bf[3][KS];
  #pragma unroll
  for (int i = 0; i < 3; ++i) if (i < NT) {
    const int g = (tbase + i) * 16 + lr;
    #pragma unroll
    for (int kk = 0; kk < KS; ++kk) {
      half8 v;
      #pragma unroll
      for (int j = 0; j < 8; ++j) {
        const int k = kk * 32 + lq * 8 + j;
        float wv = 0.f;
        if (k < INW) wv = Wih[g * INW + k];
        else if (k < BIASC) wv = Whh[g * 68 + (k - INW)];
        else if (k == BIASC) wv = bih[g] + bhh[g];
        v[j] = (_Float16)wv;
      }
      Bf[i][kk] = v;
    }
  }
  float cst[3] = {0.f, 0.f, 0.f};

  // ---- staging task precompute (t-independent offsets); 544 tasks = 512 + 32 extras ----
  int sgo, sao, sgo2, sao2;
  if constexpr (LAYER == 0) {
    const int b = tid / 34, i = tid % 34;
    sgo = b * (TT * 34) + i;  sao = b * 136 + i;
    const int u2 = 512 + tid, b2 = u2 / 34, i2 = u2 % 34;
    sgo2 = b2 * (TT * 34) + i2;  sao2 = b2 * 136 + i2;
  } else {
    const int dd = tid / 272, r = tid % 272, b = r / 17, c = r % 17;
    sgo = dd * 1088 + b * 68 + c * 4;  sao = b * 232 + dd * 68 + c * 4;
    const int u2 = 512 + tid, dd2 = u2 / 272, r2 = u2 % 272, b2 = r2 / 17, c2 = r2 % 17;
    sgo2 = dd2 * 1088 + b2 * 68 + c2 * 4;  sao2 = b2 * 232 + dd2 * 68 + c2 * 4;
  }

  // ---- prologue: zero A (AW*2 uint4 <= 464 < 512), bias col, stage step 0 ----
  if (tid < AW * 2) ((uint4*)s.A)[tid] = (uint4){0, 0, 0, 0};
  __syncthreads();
  if (tid < 16) s.A[tid * AW + BIASC] = (_Float16)1.f;
  const int t0 = d ? (TT - 1) : 0;
  if constexpr (LAYER == 0) {
    s.A[sao] = (_Float16)xg[sgo + t0 * 34];
    if (tid < 32) s.A[sao2] = (_Float16)xg[sgo2 + t0 * 34];
  } else {
    *(uint2*)&s.A[sao] = *(const uint2*)&h0w[sgo + t0 * 2176];
    if (tid < 32) *(uint2*)&s.A[sao2] = *(const uint2*)&h0w[sgo2 + t0 * 2176];
  }
  __syncthreads();

  #pragma unroll 1
  for (int st = 0; st < TT; ++st) {
    const int t  = d ? (TT - 1 - st) : st;
    const int tn = d ? (t - 1) : (t + 1);

    // ---- prefetch next step's staging into registers ----
    float xp0 = 0.f, xp1 = 0.f;
    uint2 hp0 = {0, 0}, hp1 = {0, 0};
    if (st < TT - 1) {
      if constexpr (LAYER == 0) {
        xp0 = xg[sgo + tn * 34];
        if (tid < 32) xp1 = xg[sgo2 + tn * 34];
      } else {
        hp0 = *(const uint2*)&h0w[sgo + tn * 2176];
        if (tid < 32) hp1 = *(const uint2*)&h0w[sgo2 + tn * 2176];
      }
    }

    // ---- MFMA: gates(16x272) = A(16xK) . B(Kx272) ----
    f32x4 acc[3];
    #pragma unroll
    for (int i = 0; i < 3; ++i) acc[i] = (f32x4){0.f, 0.f, 0.f, 0.f};
    #pragma unroll
    for (int kk = 0; kk < KS; ++kk) {
      const half8 a = *(const half8*)&s.A[lr * AW + kk * 32 + lq * 8];
      #pragma unroll
      for (int i = 0; i < 3; ++i) if (i < NT)
        acc[i] = __builtin_amdgcn_mfma_f32_16x16x32_f16(a, Bf[i][kk], acc[i], 0, 0, 0);
    }
    // C/D: col = lane&15 (gate within tile), row = lq*4+r (batch)
    #pragma unroll
    for (int i = 0; i < 3; ++i) if (i < NT) {
      const int g = (tbase + i) * 16 + lr;
      #pragma unroll
      for (int r = 0; r < 4; ++r)
        s.gates[g * 17 + lq * 4 + r] = acc[i][r];
    }
    __syncthreads();

    // ---- elementwise: thread owns (b_, j = m_ / m_+32 / m_+64 if m_<4) ----
    #pragma unroll
    for (int q = 0; q < 3; ++q) {
      if (q < 2 || m_ < 4) {
        const int j = m_ + 32 * q;
        const float gi = s.gates[j * 17 + b_];
        const float gf = s.gates[(68 + j) * 17 + b_];
        const float gg = s.gates[(136 + j) * 17 + b_];
        const float go = s.gates[(204 + j) * 17 + b_];
        const float ii = sigm(gi), ff = sigm(gf), g2 = tanh_s(gg), oo = sigm(go);
        const float cc = ff * cst[q] + ii * g2;
        cst[q] = cc;
        const float h = oo * tanh_s(cc);
        const _Float16 h16 = (_Float16)h;
        s.A[b_ * AW + HOFF + j] = h16;
        if constexpr (LAYER == 0) {
          h0w[t * 2176 + d * 1088 + b_ * 68 + j] = h16;   // contiguous full-line spine
        } else {
          const int fo = t * 136 + d * 68 + j;
          #pragma unroll
          for (int k = 0; k < 5; ++k) yk[k] += h * fcw[k * 6528 + fo];
        }
      }
    }
    // ---- staging writes for next step ----
    if (st < TT - 1) {
      if constexpr (LAYER == 0) {
        s.A[sao] = (_Float16)xp0;
        if (tid < 32) s.A[sao2] = (_Float16)xp1;
      } else {
        *(uint2*)&s.A[sao] = hp0;
        if (tid < 32) *(uint2*)&s.A[sao2] = hp1;
      }
    }
    __syncthreads();
  }
}

__global__ __attribute__((amdgpu_flat_work_group_size(NTHR, NTHR)))
void lstm_fc_kernel(
    const float* __restrict__ x,
    const float* __restrict__ Wih0f, const float* __restrict__ Whh0f,
    const float* __restrict__ bih0f, const float* __restrict__ bhh0f,
    const float* __restrict__ Wih0b, const float* __restrict__ Whh0b,
    const float* __restrict__ bih0b, const float* __restrict__ bhh0b,
    const float* __restrict__ Wih1f, const float* __restrict__ Whh1f,
    const float* __restrict__ bih1f, const float* __restrict__ bhh1f,
    const float* __restrict__ Wih1b, const float* __restrict__ Whh1b,
    const float* __restrict__ bih1b, const float* __restrict__ bhh1b,
    const float* __restrict__ fcw, const float* __restrict__ fcb,
    float* __restrict__ out, _Float16* __restrict__ ws)
{
  __shared__ Smem s;
  const int tid = threadIdx.x;
  _Float16* h0w = ws + (size_t)blockIdx.x * H0_SLICE;

  for (int grp = blockIdx.x; grp < NGRP; grp += gridDim.x) {
    const float* xg = x + (size_t)grp * (BT * TT * 34);
    float yk[5] = {0.f, 0.f, 0.f, 0.f, 0.f};

    pass_lstm<0>(s, 0, Wih0f, Whh0f, bih0f, bhh0f, xg, nullptr, h0w, yk);
    pass_lstm<0>(s, 1, Wih0b, Whh0b, bih0b, bhh0b, xg, nullptr, h0w, yk);
    pass_lstm<1>(s, 0, Wih1f, Whh1f, bih1f, bhh1f, nullptr, fcw, h0w, yk);
    pass_lstm<1>(s, 1, Wih1b, Whh1b, bih1b, bhh1b, nullptr, fcw, h0w, yk);

    // ---- FC epilogue: dump per-thread partials, 80 threads reduce ----
    {
      const int b_ = tid >> 5, m_ = tid & 31;
      #pragma unroll
      for (int k = 0; k < 5; ++k) s.yscr[(b_ * 5 + k) * 32 + m_] = yk[k];
    }
    __syncthreads();
    if (tid < 80) {
      const int b = tid / 5, k = tid - (tid / 5) * 5;
      float v = fcb[k];
      #pragma unroll 8
      for (int m = 0; m < 32; ++m) v += s.yscr[(b * 5 + k) * 32 + m];
      out[(size_t)(grp * BT + b) * 5 + k] = v;
    }
    __syncthreads();
  }
}

extern "C" void kernel_launch(void* const* d_in, const int* in_sizes, int n_in,
                              void* d_out, int out_size, void* d_ws, size_t ws_size,
                              hipStream_t stream) {
  (void)in_sizes; (void)n_in; (void)out_size;
  static_assert(sizeof(Smem) <= 60 * 1024, "LDS budget for 2 blocks/CU");

  const float* x     = (const float*)d_in[0];
  const float* Wih0f = (const float*)d_in[1];
  const float* Whh0f = (const float*)d_in[2];
  const float* bih0f = (const float*)d_in[3];
  const float* bhh0f = (const float*)d_in[4];
  const float* Wih0b = (const float*)d_in[5];
  const float* Whh0b = (const float*)d_in[6];
  const float* bih0b = (const float*)d_in[7];
  const float* bhh0b = (const float*)d_in[8];
  const float* Wih1f = (const float*)d_in[9];
  const float* Whh1f = (const float*)d_in[10];
  const float* bih1f = (const float*)d_in[11];
  const float* bhh1f = (const float*)d_in[12];
  const float* Wih1b = (const float*)d_in[13];
  const float* Whh1b = (const float*)d_in[14];
  const float* bih1b = (const float*)d_in[15];
  const float* bhh1b = (const float*)d_in[16];
  const float* fcw   = (const float*)d_in[17];
  const float* fcb   = (const float*)d_in[18];
  float* out = (float*)d_out;

  int slices = (int)(ws_size / (size_t)(H0_SLICE * 2));
  int grid = slices < 1 ? 1 : (slices > MAXGRID ? MAXGRID : slices);

  lstm_fc_kernel<<<dim3(grid), dim3(NTHR), 0, stream>>>(x,
      Wih0f, Whh0f, bih0f, bhh0f, Wih0b, Whh0b, bih0b, bhh0b,
      Wih1f, Whh1f, bih1f, bhh1f, Wih1b, Whh1b, bih1b, bhh1b,
      fcw, fcb, out, (_Float16*)d_ws);
}